// Round 9
// baseline (2213.056 us; speedup 1.0000x reference)
//
#include <hip/hip_runtime.h>

// VQ straight-through: B=32, V=4096, D=64, K=512. N = 131072 rows.
// Outputs (flat, concatenated): z_q_st [N,D] f32, z_q [N,D] f32, indices [N] (as f32).
//
// Correctness contract (established R2/R3, passing): replicate numpy fp32 bitwise —
//  - sums of squares: numpy pairwise_sum scalar 8-accumulator order, products
//    rounded separately (no FMA contraction into the sum)
//  - z@e.T dots: sequential single-accumulator FMA chain over d=0..63 (BLAS)
//  - d2 = fl(fl(A - 2*dot) + C); argmin: global first-min (min value, tie -> min k)
//
// R14: R13 (207us) validated the Mr=4 x Nr=16 register tile but died on
// occupancy (99 KB LDS -> 1 block/CU -> 2 waves/SIMD -> naked ds_read/barrier
// latency). Fix: e comes straight from GLOBAL (uniform address -> one
// L1-broadcast transaction per 16B; 16 loads per 512 FMA-cyc, bases hoisted
// per group) and e_lds is deleted. z_lds is read-only during the scan, so the
// k-loop has ZERO barriers. LDS = z 64K + A 1K + nrm 2K = 67 KB ->
// 2 blocks/CU = 4 waves/SIMD (2x R13's latency hiding). Merge buffers alias
// the dead z_lds. Numeric op sequence identical to R13.

#define VQ_N (32 * 4096)
#define VQ_D 64
#define VQ_K 512
#define ROWS 256     // rows per block
#define THREADS 512  // 8 waves
#define NG 4         // code-groups per wave
#define NR 16        // codes per wave per group
#define MR 4         // rows per lane = ROWS / 64

// Rounding barrier: forbids FMA contraction / reassociation through x.
__device__ __forceinline__ float freeze(float x) {
  asm volatile("" : "+v"(x));
  return x;
}

// ---- kernel 1: C_k = np.sum(emb*emb, -1) in numpy fp32 order ----
__global__ __launch_bounds__(256) void vq_norms_kernel(
    const float* __restrict__ emb, float* __restrict__ nrm) {
  int k = blockIdx.x * blockDim.x + threadIdx.x;
  if (k < VQ_K) {
    const float* e = emb + k * VQ_D;
    float r0 = freeze(e[0] * e[0]), r1 = freeze(e[1] * e[1]);
    float r2 = freeze(e[2] * e[2]), r3 = freeze(e[3] * e[3]);
    float r4 = freeze(e[4] * e[4]), r5 = freeze(e[5] * e[5]);
    float r6 = freeze(e[6] * e[6]), r7 = freeze(e[7] * e[7]);
#pragma unroll
    for (int i = 8; i < VQ_D; i += 8) {
      r0 += freeze(e[i + 0] * e[i + 0]); r1 += freeze(e[i + 1] * e[i + 1]);
      r2 += freeze(e[i + 2] * e[i + 2]); r3 += freeze(e[i + 3] * e[i + 3]);
      r4 += freeze(e[i + 4] * e[i + 4]); r5 += freeze(e[i + 5] * e[i + 5]);
      r6 += freeze(e[i + 6] * e[i + 6]); r7 += freeze(e[i + 7] * e[i + 7]);
    }
    nrm[k] = ((r0 + r1) + (r2 + r3)) + ((r4 + r5) + (r6 + r7));
  }
}

// ---- kernel 2: main — 256 rows/block, 8 waves, Mr=4 x Nr=16 reg tile,
// ----            z from LDS (dense), e from global (L1 broadcast) ----
__global__ __launch_bounds__(THREADS, 4) void vq_main_kernel(
    const float* __restrict__ z_e, const float* __restrict__ emb,
    const float* __restrict__ nrm, float* __restrict__ out_st,
    float* __restrict__ out_q, float* __restrict__ out_idx) {
  __shared__ float4 z_lds[16][ROWS];  // 64 KB [d-chunk][row]
  __shared__ float A_lds[ROWS];       // 1 KB
  __shared__ float nrm_lds[VQ_K];     // 2 KB

  const int tid = threadIdx.x;
  const int lane = tid & 63;
  const int w = __builtin_amdgcn_readfirstlane(tid >> 6);  // wave id 0..7
  const size_t row0 = (size_t)blockIdx.x * ROWS;

  // Stage z tile (4096 float4, 8/thread, coalesced) + nrm (1 float/thread).
  const float4* zg = (const float4*)(z_e + row0 * VQ_D);
#pragma unroll
  for (int t = 0; t < 8; ++t) {
    int i = t * THREADS + tid;
    z_lds[i & 15][i >> 4] = zg[i];
  }
  nrm_lds[tid] = nrm[tid];  // VQ_K == THREADS
  __syncthreads();

  // A-phase (verified since R10): numpy 8-accumulator order, acc j gets
  // d ≡ j mod 8; chunk pair (2c,2c+1) supplies d = 8c..8c+7.
  if (tid < ROWS) {
    float4 p0 = z_lds[0][tid], p1 = z_lds[1][tid];
    float r0 = freeze(p0.x * p0.x), r1 = freeze(p0.y * p0.y);
    float r2 = freeze(p0.z * p0.z), r3 = freeze(p0.w * p0.w);
    float r4 = freeze(p1.x * p1.x), r5 = freeze(p1.y * p1.y);
    float r6 = freeze(p1.z * p1.z), r7 = freeze(p1.w * p1.w);
#pragma unroll
    for (int c = 2; c < 16; c += 2) {
      float4 q0 = z_lds[c][tid], q1 = z_lds[c + 1][tid];
      r0 += freeze(q0.x * q0.x); r1 += freeze(q0.y * q0.y);
      r2 += freeze(q0.z * q0.z); r3 += freeze(q0.w * q0.w);
      r4 += freeze(q1.x * q1.x); r5 += freeze(q1.y * q1.y);
      r6 += freeze(q1.z * q1.z); r7 += freeze(q1.w * q1.w);
    }
    A_lds[tid] = ((r0 + r1) + (r2 + r3)) + ((r4 + r5) + (r6 + r7));
  }
  __syncthreads();

  float Ar[MR];
#pragma unroll
  for (int m = 0; m < MR; ++m) Ar[m] = A_lds[lane + 64 * m];

  float bestv[MR];
  int besti[MR];
#pragma unroll
  for (int m = 0; m < MR; ++m) { bestv[m] = 3.4e38f; besti[m] = 0; }

  const float4* e4 = (const float4*)emb;  // [K*16] float4, 128 KB (L1/L2-hot)

  // k-loop: NO barriers, NO staging. Wave w owns codes {g*128 + 8j + w}.
  for (int g = 0; g < NG; ++g) {
    float acc[MR][NR];
#pragma unroll
    for (int m = 0; m < MR; ++m)
#pragma unroll
      for (int j = 0; j < NR; ++j) acc[m][j] = 0.f;

#pragma unroll
    for (int c = 0; c < 16; ++c) {  // d = 4c..4c+3
      float4 zr[MR];
#pragma unroll
      for (int m = 0; m < MR; ++m) zr[m] = z_lds[c][lane + 64 * m];
#pragma unroll
      for (int j = 0; j < NR; ++j) {
        // Uniform address -> one broadcast L1 transaction per wave.
        float4 f = e4[(size_t)(g * 128 + 8 * j + w) * 16 + c];
#pragma unroll
        for (int m = 0; m < MR; ++m) {
          // Sequential single-accumulator chain, d ascending (BLAS order).
          acc[m][j] = fmaf(zr[m].x, f.x, acc[m][j]);
          acc[m][j] = fmaf(zr[m].y, f.y, acc[m][j]);
          acc[m][j] = fmaf(zr[m].z, f.z, acc[m][j]);
          acc[m][j] = fmaf(zr[m].w, f.w, acc[m][j]);
        }
      }
    }

    // d2 = fl(fl(A - 2*dot) + C); 2*dot exact => fmaf(-2,a,A) == fl(A-2a).
    // Within-wave k ascends over (g, j) -> strict < keeps wave-subset
    // first-min.
#pragma unroll
    for (int j = 0; j < NR; ++j) {
      const int k = g * 128 + 8 * j + w;
      const float C = nrm_lds[k];
#pragma unroll
      for (int m = 0; m < MR; ++m) {
        float tv = fmaf(-2.0f, acc[m][j], Ar[m]) + C;
        if (tv < bestv[m]) { bestv[m] = tv; besti[m] = k; }
      }
    }
  }

  // z_lds is dead from here; alias the cross-wave merge buffers into it.
  __syncthreads();  // all waves done reading z_lds
  float* zf = (float*)z_lds;
  float* sv = zf;                  // [8][256] values, 8 KB
  int* si = (int*)(zf + 8 * ROWS); // [8][256] indices, 8 KB
#pragma unroll
  for (int m = 0; m < MR; ++m) {
    sv[w * ROWS + lane + 64 * m] = bestv[m];
    si[w * ROWS + lane + 64 * m] = besti[m];
  }
  __syncthreads();

  // Lexicographic (value, index) merge == np.argmin first-min (R11-verified).
  if (tid < ROWS) {
    float v = sv[tid];
    int b = si[tid];
#pragma unroll
    for (int q = 1; q < 8; ++q) {
      float vq = sv[q * ROWS + tid];
      int bq = si[q * ROWS + tid];
      if (vq < v || (vq == v && bq < b)) { v = vq; b = bq; }
    }
    ((int*)A_lds)[tid] = b;  // A_lds dead -> reuse as s_best
    out_idx[row0 + tid] = (float)b;
  }
  __syncthreads();

  // Coalesced output writes: 256 rows x 16 float4 per array = 4096 f4,
  // 512 threads -> 8 iterations.
  const int* s_best = (const int*)A_lds;
  const size_t base4 = row0 * 16;
  float4* o0 = (float4*)out_st;
  float4* o1 = (float4*)out_q;
#pragma unroll
  for (int t = 0; t < 8; ++t) {
    int i = t * THREADS + tid;
    int r = i >> 4, j = i & 15;
    float4 v = e4[s_best[r] * 16 + j];
    o0[base4 + i] = v;
    o1[base4 + i] = v;
  }
}

extern "C" void kernel_launch(void* const* d_in, const int* in_sizes, int n_in,
                              void* d_out, int out_size, void* d_ws,
                              size_t ws_size, hipStream_t stream) {
  const float* z_e = (const float*)d_in[0];  // [N, D] fp32
  const float* emb = (const float*)d_in[1];  // [K, D] fp32
  float* nrm = (float*)d_ws;                 // [K] fp32 scratch

  float* out_st = (float*)d_out;                 // [N, D]
  float* out_q = out_st + (size_t)VQ_N * VQ_D;   // [N, D]
  float* out_idx = out_q + (size_t)VQ_N * VQ_D;  // [N] as float

  vq_norms_kernel<<<(VQ_K + 255) / 256, 256, 0, stream>>>(emb, nrm);
  vq_main_kernel<<<VQ_N / ROWS, THREADS, 0, stream>>>(z_e, emb, nrm, out_st,
                                                      out_q, out_idx);
}

// Round 10
// 265.343 us; speedup vs baseline: 8.3404x; 8.3404x over previous
//
#include <hip/hip_runtime.h>

// VQ straight-through: B=32, V=4096, D=64, K=512. N = 131072 rows.
// Outputs (flat, concatenated): z_q_st [N,D] f32, z_q [N,D] f32, indices [N] (as f32).
//
// Correctness contract (established R2/R3, passing): replicate numpy fp32 bitwise —
//  - sums of squares: numpy pairwise_sum scalar 8-accumulator order, products
//    rounded separately (no FMA contraction into the sum)
//  - z@e.T dots: sequential single-accumulator FMA chain over d=0..63 (BLAS)
//  - d2 = fl(fl(A - 2*dot) + C); argmin: global first-min (min value, tie -> min k)
//
// R15: R14's 5.9GB FETCH / 720MB WRITE / VALU 6.6% at VGPR=64 was ACC SPILL:
// launch_bounds(512,4) capped the budget at 128, the allocator settled at 64
// and pushed the Mr4xNr16 (64-acc) tile to scratch (~536MB spill stores =
// the observed write excess). Design-space map so far: 64-acc spills (R13/14),
// Mr=1 starves reuse (R10 166us), 99KB LDS kills occupancy (R13). Open cell:
//  - Mr=2 x Nr=16 -> 32 accs (safely allocatable, ~70 VGPR total);
//  - e from UNIFORM GLOBAL (R14's e-path — never the culprit): zero LDS-pipe
//    cost, zero per-lane address VALU, compiler can scalarize to s_load;
//  - z in LDS (32KB), k-loop has no barriers; ROWS=128, 8 waves, 1024 blocks.
// Pipe model per c-chunk: 2 dense z ds_reads + 16 uniform e-loads feed
// 128 FMA-inst (256 cyc): LDS load ~0.34, VMEM issue ~0.25 — both pipes <1,
// no spill. LDS 34.5KB + ~70 VGPR -> ~3 blocks/CU (~24 waves, 75% occ).
// Numeric op sequence identical to R13/R14 (both passed numerics).

#define VQ_N (32 * 4096)
#define VQ_D 64
#define VQ_K 512
#define ROWS 128     // rows per block
#define THREADS 512  // 8 waves
#define NG 4         // code-groups per wave
#define NR 16        // codes per wave per group (acc = MR*NR = 32)
#define MR 2         // rows per lane = ROWS / 64

// Rounding barrier: forbids FMA contraction / reassociation through x.
__device__ __forceinline__ float freeze(float x) {
  asm volatile("" : "+v"(x));
  return x;
}

// ---- kernel 1: C_k = np.sum(emb*emb, -1) in numpy fp32 order ----
__global__ __launch_bounds__(256) void vq_norms_kernel(
    const float* __restrict__ emb, float* __restrict__ nrm) {
  int k = blockIdx.x * blockDim.x + threadIdx.x;
  if (k < VQ_K) {
    const float* e = emb + k * VQ_D;
    float r0 = freeze(e[0] * e[0]), r1 = freeze(e[1] * e[1]);
    float r2 = freeze(e[2] * e[2]), r3 = freeze(e[3] * e[3]);
    float r4 = freeze(e[4] * e[4]), r5 = freeze(e[5] * e[5]);
    float r6 = freeze(e[6] * e[6]), r7 = freeze(e[7] * e[7]);
#pragma unroll
    for (int i = 8; i < VQ_D; i += 8) {
      r0 += freeze(e[i + 0] * e[i + 0]); r1 += freeze(e[i + 1] * e[i + 1]);
      r2 += freeze(e[i + 2] * e[i + 2]); r3 += freeze(e[i + 3] * e[i + 3]);
      r4 += freeze(e[i + 4] * e[i + 4]); r5 += freeze(e[i + 5] * e[i + 5]);
      r6 += freeze(e[i + 6] * e[i + 6]); r7 += freeze(e[i + 7] * e[i + 7]);
    }
    nrm[k] = ((r0 + r1) + (r2 + r3)) + ((r4 + r5) + (r6 + r7));
  }
}

// ---- kernel 2: main — 128 rows/block, 8 waves, Mr=2 x Nr=16 reg tile,
// ----            z from LDS (dense reads), e from uniform global ----
__global__ __launch_bounds__(THREADS, 2) void vq_main_kernel(
    const float* __restrict__ z_e, const float* __restrict__ emb,
    const float* __restrict__ nrm, float* __restrict__ out_st,
    float* __restrict__ out_q, float* __restrict__ out_idx) {
  __shared__ float4 z_lds[16][ROWS];  // 32 KB [d-chunk][row]
  __shared__ float A_lds[ROWS];       // 0.5 KB
  __shared__ float nrm_lds[VQ_K];     // 2 KB

  const int tid = threadIdx.x;
  const int lane = tid & 63;
  const int w = __builtin_amdgcn_readfirstlane(tid >> 6);  // wave id 0..7
  const size_t row0 = (size_t)blockIdx.x * ROWS;

  // Stage z tile (2048 float4, 4/thread, coalesced) + nrm (1 float/thread).
  const float4* zg = (const float4*)(z_e + row0 * VQ_D);
#pragma unroll
  for (int t = 0; t < 4; ++t) {
    int i = t * THREADS + tid;
    z_lds[i & 15][i >> 4] = zg[i];
  }
  nrm_lds[tid] = nrm[tid];  // VQ_K == THREADS
  __syncthreads();

  // A-phase (verified since R10): numpy 8-accumulator order, acc j gets
  // d ≡ j mod 8; chunk pair (2c,2c+1) supplies d = 8c..8c+7.
  if (tid < ROWS) {
    float4 p0 = z_lds[0][tid], p1 = z_lds[1][tid];
    float r0 = freeze(p0.x * p0.x), r1 = freeze(p0.y * p0.y);
    float r2 = freeze(p0.z * p0.z), r3 = freeze(p0.w * p0.w);
    float r4 = freeze(p1.x * p1.x), r5 = freeze(p1.y * p1.y);
    float r6 = freeze(p1.z * p1.z), r7 = freeze(p1.w * p1.w);
#pragma unroll
    for (int c = 2; c < 16; c += 2) {
      float4 q0 = z_lds[c][tid], q1 = z_lds[c + 1][tid];
      r0 += freeze(q0.x * q0.x); r1 += freeze(q0.y * q0.y);
      r2 += freeze(q0.z * q0.z); r3 += freeze(q0.w * q0.w);
      r4 += freeze(q1.x * q1.x); r5 += freeze(q1.y * q1.y);
      r6 += freeze(q1.z * q1.z); r7 += freeze(q1.w * q1.w);
    }
    A_lds[tid] = ((r0 + r1) + (r2 + r3)) + ((r4 + r5) + (r6 + r7));
  }
  __syncthreads();

  float Ar[MR];
#pragma unroll
  for (int m = 0; m < MR; ++m) Ar[m] = A_lds[lane + 64 * m];

  float bestv[MR];
  int besti[MR];
#pragma unroll
  for (int m = 0; m < MR; ++m) { bestv[m] = 3.4e38f; besti[m] = 0; }

  const float4* e4 = (const float4*)emb;  // [K*16] float4, 128 KB (L2-hot)

  // k-loop: NO barriers, NO e staging. Wave w owns codes {g*128 + 8j + w}.
  for (int g = 0; g < NG; ++g) {
    float acc[MR][NR];
#pragma unroll
    for (int m = 0; m < MR; ++m)
#pragma unroll
      for (int j = 0; j < NR; ++j) acc[m][j] = 0.f;

#pragma unroll
    for (int c = 0; c < 16; ++c) {  // d = 4c..4c+3
      float4 zr[MR];
#pragma unroll
      for (int m = 0; m < MR; ++m) zr[m] = z_lds[c][lane + 64 * m];
#pragma unroll
      for (int j = 0; j < NR; ++j) {
        // Wave-uniform address: scalarizable (s_load) or 1 broadcast
        // transaction; zero per-lane address VALU either way.
        float4 f = e4[(size_t)(g * 128 + 8 * j + w) * 16 + c];
#pragma unroll
        for (int m = 0; m < MR; ++m) {
          // Sequential single-accumulator chain, d ascending (BLAS order).
          acc[m][j] = fmaf(zr[m].x, f.x, acc[m][j]);
          acc[m][j] = fmaf(zr[m].y, f.y, acc[m][j]);
          acc[m][j] = fmaf(zr[m].z, f.z, acc[m][j]);
          acc[m][j] = fmaf(zr[m].w, f.w, acc[m][j]);
        }
      }
    }

    // d2 = fl(fl(A - 2*dot) + C); 2*dot exact => fmaf(-2,a,A) == fl(A-2a).
    // Within-wave k ascends over (g, j) -> strict < keeps wave-subset
    // first-min.
#pragma unroll
    for (int j = 0; j < NR; ++j) {
      const int k = g * 128 + 8 * j + w;
      const float C = nrm_lds[k];
#pragma unroll
      for (int m = 0; m < MR; ++m) {
        float tv = fmaf(-2.0f, acc[m][j], Ar[m]) + C;
        if (tv < bestv[m]) { bestv[m] = tv; besti[m] = k; }
      }
    }
  }

  // z_lds is dead from here; alias the cross-wave merge buffers into it.
  __syncthreads();  // all waves done reading z_lds
  float* zf = (float*)z_lds;
  float* sv = zf;                   // [8][128] values, 4 KB
  int* si = (int*)(zf + 8 * ROWS);  // [8][128] indices, 4 KB
#pragma unroll
  for (int m = 0; m < MR; ++m) {
    sv[w * ROWS + lane + 64 * m] = bestv[m];
    si[w * ROWS + lane + 64 * m] = besti[m];
  }
  __syncthreads();

  // Lexicographic (value, index) merge == np.argmin first-min (R11-verified).
  if (tid < ROWS) {
    float v = sv[tid];
    int b = si[tid];
#pragma unroll
    for (int q = 1; q < 8; ++q) {
      float vq = sv[q * ROWS + tid];
      int bq = si[q * ROWS + tid];
      if (vq < v || (vq == v && bq < b)) { v = vq; b = bq; }
    }
    ((int*)A_lds)[tid] = b;  // A_lds dead -> reuse as s_best (128 ints)
    out_idx[row0 + tid] = (float)b;
  }
  __syncthreads();

  // Coalesced output writes: 128 rows x 16 float4 per array = 2048 f4,
  // 512 threads -> 4 iterations.
  const int* s_best = (const int*)A_lds;
  const size_t base4 = row0 * 16;
  float4* o0 = (float4*)out_st;
  float4* o1 = (float4*)out_q;
#pragma unroll
  for (int t = 0; t < 4; ++t) {
    int i = t * THREADS + tid;
    int r = i >> 4, j = i & 15;
    float4 v = e4[s_best[r] * 16 + j];
    o0[base4 + i] = v;
    o1[base4 + i] = v;
  }
}

extern "C" void kernel_launch(void* const* d_in, const int* in_sizes, int n_in,
                              void* d_out, int out_size, void* d_ws,
                              size_t ws_size, hipStream_t stream) {
  const float* z_e = (const float*)d_in[0];  // [N, D] fp32
  const float* emb = (const float*)d_in[1];  // [K, D] fp32
  float* nrm = (float*)d_ws;                 // [K] fp32 scratch

  float* out_st = (float*)d_out;                 // [N, D]
  float* out_q = out_st + (size_t)VQ_N * VQ_D;   // [N, D]
  float* out_idx = out_q + (size_t)VQ_N * VQ_D;  // [N] as float

  vq_norms_kernel<<<(VQ_K + 255) / 256, 256, 0, stream>>>(emb, nrm);
  vq_main_kernel<<<VQ_N / ROWS, THREADS, 0, stream>>>(z_e, emb, nrm, out_st,
                                                      out_q, out_idx);
}